// Round 4
// baseline (123.264 us; speedup 1.0000x reference)
//
#include <hip/hip_runtime.h>

#define B_IMG 32
#define N_PIX (512 * 512)
#define NB 256            // 16 octaves x 16 sub-bins (4 mantissa bits)
#define SHIFT 19
#define LO_IDX 1840       // (exp_biased=115) << 4  => clamp range 2^-12 .. 2^3
#define BPI 64            // blocks per image
#define CHUNK (N_PIX / BPI)   // 4096 px per block
#define FIXSCALE 1048576.0f   // 2^20 fixed point for packed bin sums
#define MASK40 ((1ull << 40) - 1)

// ---------------- Pass 1: per-block partial histogram (packed u64) ----------------
// Packs per-bin {count, sum} into one u64: [63:40]=count, [39:0]=sum in 2^-20 fixed pt.
// 2 LDS copies (waves 0-1 / waves 2-3) halve same-address ds_add_u64 serialization.
__global__ __launch_bounds__(256, 8) void hist_kernel(
    const float4* __restrict__ pred, const float4* __restrict__ targ,
    const int4* __restrict__ mask, unsigned long long* __restrict__ g_part,
    double* __restrict__ accs, unsigned* __restrict__ counter) {
  __shared__ unsigned long long s_hist[2][NB];
  const int tid = threadIdx.x;
  if (tid < NB) { s_hist[0][tid] = 0ull; s_hist[1][tid] = 0ull; }
  if (blockIdx.x == 0 && tid == 0) {  // zero K2 accumulators; ordered before K2
    accs[0] = 0.0; accs[1] = 0.0; *counter = 0u;
  }
  __syncthreads();

  const int half = tid >> 7;               // waves 0-1 -> copy 0, waves 2-3 -> copy 1
  unsigned long long* hist = s_hist[half];
  const int base4 = blockIdx.x * (CHUNK / 4);

#define BIN1(pp, tt, mm)                                                     \
  if ((mm) > 0) {                                                            \
    const float e = fabsf((pp) - (tt));                                      \
    int bb = (int)(__float_as_uint(e) >> SHIFT) - LO_IDX;                    \
    bb = bb < 0 ? 0 : (bb > NB - 1 ? NB - 1 : bb);                           \
    const unsigned long long pkt =                                           \
        (1ull << 40) | (unsigned long long)__float2uint_rn(e * FIXSCALE);    \
    atomicAdd(&hist[bb], pkt);                                               \
  }

  // 2-deep software pipeline: next (p,t,m) triple in flight while binning current
  float4 p0 = pred[base4 + tid];
  float4 t0 = targ[base4 + tid];
  int4 m0 = mask[base4 + tid];
#pragma unroll
  for (int j = 0; j < 4; ++j) {
    float4 p1, t1;
    int4 m1;
    if (j < 3) {
      const int idx = base4 + (j + 1) * 256 + tid;
      p1 = pred[idx]; t1 = targ[idx]; m1 = mask[idx];
    }
    BIN1(p0.x, t0.x, m0.x)
    BIN1(p0.y, t0.y, m0.y)
    BIN1(p0.z, t0.z, m0.z)
    BIN1(p0.w, t0.w, m0.w)
    p0 = p1; t0 = t1; m0 = m1;
  }
  __syncthreads();

  // flush merged partial histogram: plain coalesced store, no atomics
  if (tid < NB)
    g_part[(size_t)blockIdx.x * NB + tid] = s_hist[0][tid] + s_hist[1][tid];
}

// ---------------- Pass 2: per-image selection + trimmed sum + final divide ----------------
__global__ __launch_bounds__(256) void finalize_kernel(
    const unsigned long long* __restrict__ g_part, double* __restrict__ accs,
    unsigned* __restrict__ counter, float* __restrict__ out) {
  const int b = blockIdx.x;
  const int tid = threadIdx.x;   // 256 threads, one bin each
  const unsigned long long* base = g_part + (size_t)b * BPI * NB;

  // reduce 64 partials for this image's bin `tid`
  unsigned long long fix = 0ull;
  unsigned c = 0u;
#pragma unroll 8
  for (int p = 0; p < BPI; ++p) {
    const unsigned long long v = base[(size_t)p * NB + tid];
    c += (unsigned)(v >> 40);
    fix += (v & MASK40);
  }
  const double s = (double)fix * (1.0 / (double)FIXSCALE);

  __shared__ unsigned s_scan[NB];
  __shared__ int s_bin;
  __shared__ unsigned s_cbelow;
  __shared__ double s_red[NB];

  s_scan[tid] = c;
  if (tid == 0) { s_bin = 0; s_cbelow = 0; }
  __syncthreads();
  // Hillis-Steele inclusive scan of counts
#pragma unroll
  for (int off = 1; off < NB; off <<= 1) {
    const unsigned add = (tid >= off) ? s_scan[tid - off] : 0u;
    __syncthreads();
    s_scan[tid] += add;
    __syncthreads();
  }
  const unsigned incl = s_scan[tid];
  const unsigned excl = incl - c;
  const unsigned M = s_scan[NB - 1];                      // all valid px land in a bin
  const unsigned k = (unsigned)floorf(0.8f * (float)M);   // matches ref's f32 floor

  if (k > 0 && excl < k && k <= incl) { s_bin = tid; s_cbelow = excl; }
  __syncthreads();

  const int bstar = s_bin;
  double acc = (tid < bstar) ? s : 0.0;   // full bins below boundary: exact sums
  if (tid == bstar && k > 0) {
    const unsigned r = k - s_cbelow;      // 1 <= r <= c
    double part;
    if (r >= c) {
      part = s;                           // exact: whole bin kept
    } else {
      const float lo = __uint_as_float((unsigned)(bstar + LO_IDX) << SHIFT);
      const double mean = s / (double)c;
      double h = mean - (double)lo;
      if (h < 0.0) h = 0.0;
      part = (double)r * (double)lo + ((double)r * (double)r / (double)c) * h;
      if (part > s) part = s;
    }
    acc += part;
  }

  // block reduce doubles
  s_red[tid] = acc;
  __syncthreads();
  for (int st = 128; st > 0; st >>= 1) {
    if (tid < st) s_red[tid] += s_red[tid + st];
    __syncthreads();
  }
  if (tid == 0) {
    atomicAdd(&accs[0], s_red[0]);                     // numerator
    atomicAdd(&accs[1], (double)(0.8f * (float)M));    // divisor term
    __threadfence();
    const unsigned old = atomicAdd(counter, 1u);
    if (old == (unsigned)(B_IMG - 1)) {                // last block finalizes
      __threadfence();
      const double num = atomicAdd(&accs[0], 0.0);
      const double den = atomicAdd(&accs[1], 0.0);
      const double r = (den == 0.0) ? 0.0 : num / fmax(den, 1e-30);
      out[0] = (float)r;
    }
  }
}

extern "C" void kernel_launch(void* const* d_in, const int* in_sizes, int n_in,
                              void* d_out, int out_size, void* d_ws, size_t ws_size,
                              hipStream_t stream) {
  const float4* pred = (const float4*)d_in[0];
  const float4* targ = (const float4*)d_in[1];
  const int4* mask = (const int4*)d_in[2];
  float* out = (float*)d_out;

  char* ws = (char*)d_ws;
  unsigned long long* g_part = (unsigned long long*)ws;            // 2048*256*8 = 4 MB
  double* accs = (double*)(ws + (size_t)B_IMG * BPI * NB * 8);     // 16 B
  unsigned* counter = (unsigned*)(ws + (size_t)B_IMG * BPI * NB * 8 + 16);

  hist_kernel<<<B_IMG * BPI, 256, 0, stream>>>(pred, targ, mask, g_part, accs, counter);
  finalize_kernel<<<B_IMG, 256, 0, stream>>>(g_part, accs, counter, out);
}

// Round 5
// 122.909 us; speedup vs baseline: 1.0029x; 1.0029x over previous
//
#include <hip/hip_runtime.h>

#define B_IMG 32
#define N_PIX (512 * 512)
#define NB 256            // 16 octaves x 16 sub-bins (4 mantissa bits)
#define SHIFT 19
#define LO_IDX 1840       // (exp_biased=115) << 4  => clamp range 2^-12 .. 2^3
#define BPI 64            // blocks per image
#define CHUNK (N_PIX / BPI)   // 4096 px per block
#define NCOPY 8               // one histogram copy per half-wave (32 lanes)
#define FIXSCALE 256.0f       // 2^-8 fixed point for in-LDS sums
#define CNT_SHIFT 22          // u32 pack: [31:22]=count (<=512), [21:0]=sum_fix8 (<2^22)
#define SUM_MASK 0x3FFFFFu
#define MASK40 ((1ull << 40) - 1)

// ---------------- Pass 1: per-block partial histogram ----------------
// In-loop atomic is ds_add_u32 (1 bank) instead of ds_add_u64 (2 banks):
// pkt = (1<<22) | round(e*256). 8 half-wave copies bound count<=512, sum<2^22.
__global__ __launch_bounds__(256, 8) void hist_kernel(
    const float4* __restrict__ pred, const float4* __restrict__ targ,
    const int4* __restrict__ mask, unsigned long long* __restrict__ g_part,
    double* __restrict__ accs, unsigned* __restrict__ counter) {
  __shared__ unsigned s_hist[NCOPY][NB];   // 8 KB
  const int tid = threadIdx.x;
#pragma unroll
  for (int w = 0; w < NCOPY; ++w) s_hist[w][tid] = 0u;
  if (blockIdx.x == 0 && tid == 0) {  // zero K2 accumulators; ordered before K2
    accs[0] = 0.0; accs[1] = 0.0; *counter = 0u;
  }
  __syncthreads();

  unsigned* hist = s_hist[tid >> 5];   // per half-wave copy
  const int base4 = blockIdx.x * (CHUNK / 4);

#define BIN1(pp, tt, mm)                                                     \
  if ((mm) > 0) {                                                            \
    const float e = fabsf((pp) - (tt));                                      \
    int bb = (int)(__float_as_uint(e) >> SHIFT) - LO_IDX;                    \
    bb = bb < 0 ? 0 : (bb > NB - 1 ? NB - 1 : bb);                           \
    unsigned fx = __float2uint_rn(e * FIXSCALE);                             \
    fx = fx > 4095u ? 4095u : fx;                                            \
    atomicAdd(&hist[bb], (1u << CNT_SHIFT) | fx);                            \
  }

  // 2-deep software pipeline: next (p,t,m) triple in flight while binning current
  float4 p0 = pred[base4 + tid];
  float4 t0 = targ[base4 + tid];
  int4 m0 = mask[base4 + tid];
#pragma unroll
  for (int j = 0; j < 4; ++j) {
    float4 p1, t1;
    int4 m1;
    if (j < 3) {
      const int idx = base4 + (j + 1) * 256 + tid;
      p1 = pred[idx]; t1 = targ[idx]; m1 = mask[idx];
    }
    BIN1(p0.x, t0.x, m0.x)
    BIN1(p0.y, t0.y, m0.y)
    BIN1(p0.z, t0.z, m0.z)
    BIN1(p0.w, t0.w, m0.w)
    p0 = p1; t0 = t1; m0 = m1;
  }
  __syncthreads();

  // merge 8 copies, flush as u64 partial: [63:40]=cnt, [39:0]=sum in 2^-8 units
  unsigned cnt = 0, sum8 = 0;
#pragma unroll
  for (int w = 0; w < NCOPY; ++w) {
    const unsigned v = s_hist[w][tid];
    cnt += v >> CNT_SHIFT;
    sum8 += v & SUM_MASK;
  }
  g_part[(size_t)blockIdx.x * NB + tid] =
      ((unsigned long long)cnt << 40) | (unsigned long long)sum8;
}

// ---------------- Pass 2: per-image selection + trimmed sum + final divide ----------------
__global__ __launch_bounds__(256) void finalize_kernel(
    const unsigned long long* __restrict__ g_part, double* __restrict__ accs,
    unsigned* __restrict__ counter, float* __restrict__ out) {
  const int b = blockIdx.x;
  const int tid = threadIdx.x;   // 256 threads, one bin each
  const unsigned long long* base = g_part + (size_t)b * BPI * NB;

  // reduce 64 partials for this image's bin `tid`
  unsigned long long fix = 0ull;
  unsigned c = 0u;
#pragma unroll 8
  for (int p = 0; p < BPI; ++p) {
    const unsigned long long v = base[(size_t)p * NB + tid];
    c += (unsigned)(v >> 40);
    fix += (v & MASK40);
  }
  const double s = (double)fix * (1.0 / (double)FIXSCALE);

  __shared__ unsigned s_scan[NB];
  __shared__ int s_bin;
  __shared__ unsigned s_cbelow;
  __shared__ double s_red[NB];

  s_scan[tid] = c;
  if (tid == 0) { s_bin = 0; s_cbelow = 0; }
  __syncthreads();
  // Hillis-Steele inclusive scan of counts
#pragma unroll
  for (int off = 1; off < NB; off <<= 1) {
    const unsigned add = (tid >= off) ? s_scan[tid - off] : 0u;
    __syncthreads();
    s_scan[tid] += add;
    __syncthreads();
  }
  const unsigned incl = s_scan[tid];
  const unsigned excl = incl - c;
  const unsigned M = s_scan[NB - 1];                      // all valid px land in a bin
  const unsigned k = (unsigned)floorf(0.8f * (float)M);   // matches ref's f32 floor

  if (k > 0 && excl < k && k <= incl) { s_bin = tid; s_cbelow = excl; }
  __syncthreads();

  const int bstar = s_bin;
  double acc = (tid < bstar) ? s : 0.0;   // full bins below boundary: exact sums
  if (tid == bstar && k > 0) {
    const unsigned r = k - s_cbelow;      // 1 <= r <= c
    double part;
    if (r >= c) {
      part = s;                           // exact: whole bin kept
    } else {
      const float lo = __uint_as_float((unsigned)(bstar + LO_IDX) << SHIFT);
      const double mean = s / (double)c;
      double h = mean - (double)lo;
      if (h < 0.0) h = 0.0;
      part = (double)r * (double)lo + ((double)r * (double)r / (double)c) * h;
      if (part > s) part = s;
    }
    acc += part;
  }

  // block reduce doubles
  s_red[tid] = acc;
  __syncthreads();
  for (int st = 128; st > 0; st >>= 1) {
    if (tid < st) s_red[tid] += s_red[tid + st];
    __syncthreads();
  }
  if (tid == 0) {
    atomicAdd(&accs[0], s_red[0]);                     // numerator
    atomicAdd(&accs[1], (double)(0.8f * (float)M));    // divisor term
    __threadfence();
    const unsigned old = atomicAdd(counter, 1u);
    if (old == (unsigned)(B_IMG - 1)) {                // last block finalizes
      __threadfence();
      const double num = atomicAdd(&accs[0], 0.0);
      const double den = atomicAdd(&accs[1], 0.0);
      const double r = (den == 0.0) ? 0.0 : num / fmax(den, 1e-30);
      out[0] = (float)r;
    }
  }
}

extern "C" void kernel_launch(void* const* d_in, const int* in_sizes, int n_in,
                              void* d_out, int out_size, void* d_ws, size_t ws_size,
                              hipStream_t stream) {
  const float4* pred = (const float4*)d_in[0];
  const float4* targ = (const float4*)d_in[1];
  const int4* mask = (const int4*)d_in[2];
  float* out = (float*)d_out;

  char* ws = (char*)d_ws;
  unsigned long long* g_part = (unsigned long long*)ws;            // 2048*256*8 = 4 MB
  double* accs = (double*)(ws + (size_t)B_IMG * BPI * NB * 8);     // 16 B
  unsigned* counter = (unsigned*)(ws + (size_t)B_IMG * BPI * NB * 8 + 16);

  hist_kernel<<<B_IMG * BPI, 256, 0, stream>>>(pred, targ, mask, g_part, accs, counter);
  finalize_kernel<<<B_IMG, 256, 0, stream>>>(g_part, accs, counter, out);
}